// Round 4
// baseline (112.609 us; speedup 1.0000x reference)
//
#include <hip/hip_runtime.h>
#include <math.h>

#define N_QUBITS 11
#define N_LAYERS 2
#define DIM 2048
#define N_GATES (N_LAYERS * N_QUBITS)
#define WAVES_PER_BLOCK 4

typedef float v2f __attribute__((ext_vector_type(2)));

static __device__ __forceinline__ v2f splat(float s) { return (v2f){s, s}; }

// DPP quad-perm lane exchanges (VALU pipe, not DS): xor1 = [1,0,3,2] = 0xB1,
// xor2 = [2,3,0,1] = 0x4E.
static __device__ __forceinline__ float dpp_xor1(float x) {
    return __builtin_bit_cast(float, __builtin_amdgcn_mov_dpp(
        __builtin_bit_cast(int, x), 0xB1, 0xF, 0xF, true));
}
static __device__ __forceinline__ float dpp_xor2(float x) {
    return __builtin_bit_cast(float, __builtin_amdgcn_mov_dpp(
        __builtin_bit_cast(int, x), 0x4E, 0xF, 0xF, true));
}

// One wave per batch element, 4 waves per block. Statevector in VGPRs as
// packed v2f: SR[k]/SI[k] hold amplitudes n=2k,2k+1 (re/im split) -> targets
// v_pk_fma_f32 (2 FMAs/instr). Lane L holds amplitudes i = L*32 + n.
//  - qubit 0      : intra-v2f butterfly via splat-operand packed form
//  - qubits 1..4  : cross-register packed butterflies
//  - qubits 5,6   : DPP quad_perm exchange (VALU pipe)
//  - qubits 7..10 : __shfl_xor exchange (DS pipe)
//  - CNOT ladder  : fused perm i_src = j ^ (j<<1): per-component lane
//                   shuffle + register cycle renames (component-pure since
//                   f preserves bit0).
__global__ __launch_bounds__(64 * WAVES_PER_BLOCK, 4)
void pqc_sim_kernel(const float* __restrict__ theta,
                    const int* __restrict__ positions,
                    float* __restrict__ out)
{
    __shared__ float G[WAVES_PER_BLOCK][N_GATES][8]; // u00r,u00i,u01r,u01i,u10r,u10i,u11r,u11i

    const int wv  = threadIdx.x >> 6;
    const int L   = threadIdx.x & 63;
    const int b   = blockIdx.x * WAVES_PER_BLOCK + wv;
    const int pos = positions[b];

    // ---- Gate precompute: U = Rz(g) * Ry(b) * Rx(a), angles * 0.5 ----
    if (L < N_GATES) {
        const int l = L / N_QUBITS;
        const int q = L % N_QUBITS;
        const float* th = theta + (((size_t)pos * N_LAYERS + l) * (3 * N_QUBITS)) + 3 * q;
        const float a  = th[0] * 0.5f;
        const float bb = th[1] * 0.5f;
        const float g  = th[2] * 0.5f;
        float sa, ca, sb, cb, sg, cg;
        sincosf(a,  &sa, &ca);
        sincosf(bb, &sb, &cb);
        sincosf(g,  &sg, &cg);
        const float m00r =  cb * ca, m00i =  sb * sa;
        const float m01r = -sb * ca, m01i = -cb * sa;
        const float m10r =  sb * ca, m10i = -cb * sa;
        const float m11r =  cb * ca, m11i = -sb * sa;
        G[wv][L][0] = m00r * cg + m00i * sg;  G[wv][L][1] = m00i * cg - m00r * sg;
        G[wv][L][2] = m01r * cg + m01i * sg;  G[wv][L][3] = m01i * cg - m01r * sg;
        G[wv][L][4] = m10r * cg - m10i * sg;  G[wv][L][5] = m10i * cg + m10r * sg;
        G[wv][L][6] = m11r * cg - m11i * sg;  G[wv][L][7] = m11i * cg + m11r * sg;
    }
    __syncthreads();

    // ---- Register-resident state, |0...0> ----
    v2f SR[16], SI[16];
    #pragma unroll
    for (int k = 0; k < 16; ++k) { SR[k] = (v2f){0.f, 0.f}; SI[k] = (v2f){0.f, 0.f}; }
    if (L == 0) SR[0].x = 1.0f;

    const int base = (L ^ (L << 1)) & 63;

    #pragma unroll
    for (int l = 0; l < N_LAYERS; ++l) {
        const int gb = l * N_QUBITS;

        // ---- Qubit 0: intra-v2f butterfly (packed via splats) ----
        {
            const float* g0 = &G[wv][gb][0];
            const v2f C0r = (v2f){g0[0], g0[4]};  // (u00r, u10r)
            const v2f C0i = (v2f){g0[1], g0[5]};
            const v2f C1r = (v2f){g0[2], g0[6]};  // (u01r, u11r)
            const v2f C1i = (v2f){g0[3], g0[7]};
            #pragma unroll
            for (int k = 0; k < 16; ++k) {
                const v2f rx = splat(SR[k].x), ry = splat(SR[k].y);
                const v2f ix = splat(SI[k].x), iy = splat(SI[k].y);
                SR[k] = C0r * rx - C0i * ix + C1r * ry - C1i * iy;
                SI[k] = C0r * ix + C0i * rx + C1r * iy + C1i * ry;
            }
        }

        // ---- Qubits 1..4: cross-register packed butterflies ----
        #pragma unroll
        for (int q = 1; q < 5; ++q) {
            const float* gq = &G[wv][gb + q][0];
            const v2f u00r = splat(gq[0]), u00i = splat(gq[1]);
            const v2f u01r = splat(gq[2]), u01i = splat(gq[3]);
            const v2f u10r = splat(gq[4]), u10i = splat(gq[5]);
            const v2f u11r = splat(gq[6]), u11i = splat(gq[7]);
            const int qq = q - 1;
            #pragma unroll
            for (int t = 0; t < 8; ++t) {
                const int k0 = ((t >> qq) << (qq + 1)) | (t & ((1 << qq) - 1));
                const int k1 = k0 + (1 << qq);
                const v2f ar = SR[k0], ai = SI[k0];
                const v2f br = SR[k1], bi = SI[k1];
                SR[k0] = u00r * ar - u00i * ai + u01r * br - u01i * bi;
                SI[k0] = u00r * ai + u00i * ar + u01r * bi + u01i * br;
                SR[k1] = u10r * ar - u10i * ai + u11r * br - u11i * bi;
                SI[k1] = u10r * ai + u10i * ar + u11r * bi + u11i * br;
            }
        }

        // ---- Qubits 5..10: lane exchanges ----
        #pragma unroll
        for (int q = 5; q < N_QUBITS; ++q) {
            const float* gq = &G[wv][gb + q][0];
            const int t   = q - 5;
            const int bit = (L >> t) & 1;
            const float csr_s = bit ? gq[6] : gq[0];
            const float csi_s = bit ? gq[7] : gq[1];
            const float cpr_s = bit ? gq[4] : gq[2];
            const float cpi_s = bit ? gq[5] : gq[3];
            const v2f csr = splat(csr_s), csi = splat(csi_s);
            const v2f cpr = splat(cpr_s), cpi = splat(cpi_s);
            #pragma unroll
            for (int k = 0; k < 16; ++k) {
                v2f pr, pi;
                if (t == 0) {
                    pr = (v2f){dpp_xor1(SR[k].x), dpp_xor1(SR[k].y)};
                    pi = (v2f){dpp_xor1(SI[k].x), dpp_xor1(SI[k].y)};
                } else if (t == 1) {
                    pr = (v2f){dpp_xor2(SR[k].x), dpp_xor2(SR[k].y)};
                    pi = (v2f){dpp_xor2(SI[k].x), dpp_xor2(SI[k].y)};
                } else {
                    const int m = 1 << t;
                    pr = (v2f){__shfl_xor(SR[k].x, m), __shfl_xor(SR[k].y, m)};
                    pi = (v2f){__shfl_xor(SI[k].x, m), __shfl_xor(SI[k].y, m)};
                }
                const v2f ar = SR[k], ai = SI[k];
                SR[k] = csr * ar - csi * ai + cpr * pr - cpi * pi;
                SI[k] = csr * ai + csi * ar + cpr * pi + cpi * pr;
            }
        }

        // ---- Fused CNOT ladder, step (a): per-component in-place lane shuffle.
        // Register m needs src lane base ^ parity(m); m=2k -> parity(k),
        // m=2k+1 -> parity(k)^1.
        #pragma unroll
        for (int k = 0; k < 16; ++k) {
            const int l0 = base ^ (__popc((unsigned)k) & 1);
            const int l1 = l0 ^ 1;
            SR[k].x = __shfl(SR[k].x, l0);  SR[k].y = __shfl(SR[k].y, l1);
            SI[k].x = __shfl(SI[k].x, l0);  SI[k].y = __shfl(SI[k].y, l1);
        }

        // ---- step (b): register cycles s[n] <- s[(n^(n<<1))&31].
        // f preserves bit0, so cycles are component-pure. k = n>>1.
        #define CYC8E(A0,A1,A2,A3,A4,A5,A6,A7) { float t_=A0; A0=A1; A1=A2; A2=A3; A3=A4; A4=A5; A5=A6; A6=A7; A7=t_; }
        #define CYC4E(A0,A1,A2,A3) { float t_=A0; A0=A1; A1=A2; A2=A3; A3=t_; }
        #define CYC2E(A0,A1) { float t_=A0; A0=A1; A1=t_; }
        // n: 1,3,5,15,17,19,21,31 -> .y of k: 0,1,2,7,8,9,10,15
        CYC8E(SR[0].y, SR[1].y, SR[2].y, SR[7].y, SR[8].y, SR[9].y, SR[10].y, SR[15].y);
        CYC8E(SI[0].y, SI[1].y, SI[2].y, SI[7].y, SI[8].y, SI[9].y, SI[10].y, SI[15].y);
        // n: 7,9,27,13,23,25,11,29 -> .y of k: 3,4,13,6,11,12,5,14
        CYC8E(SR[3].y, SR[4].y, SR[13].y, SR[6].y, SR[11].y, SR[12].y, SR[5].y, SR[14].y);
        CYC8E(SI[3].y, SI[4].y, SI[13].y, SI[6].y, SI[11].y, SI[12].y, SI[5].y, SI[14].y);
        // n: 2,6,10,30 -> .x of k: 1,3,5,15
        CYC4E(SR[1].x, SR[3].x, SR[5].x, SR[15].x);
        CYC4E(SI[1].x, SI[3].x, SI[5].x, SI[15].x);
        // n: 4,12,20,28 -> .x of k: 2,6,10,14
        CYC4E(SR[2].x, SR[6].x, SR[10].x, SR[14].x);
        CYC4E(SI[2].x, SI[6].x, SI[10].x, SI[14].x);
        // n: 14,18,22,26 -> .x of k: 7,9,11,13
        CYC4E(SR[7].x, SR[9].x, SR[11].x, SR[13].x);
        CYC4E(SI[7].x, SI[9].x, SI[11].x, SI[13].x);
        // n: 8,24 -> .x of k: 4,12
        CYC2E(SR[4].x, SR[12].x);
        CYC2E(SI[4].x, SI[12].x);
        #undef CYC8E
        #undef CYC4E
        #undef CYC2E
    }

    // ---- Epilogue: real part; lane L owns 32 consecutive floats ----
    float* orow = out + (size_t)b * DIM + L * 32;
    #pragma unroll
    for (int k = 0; k < 8; ++k) {
        *(float4*)(orow + 4 * k) =
            make_float4(SR[2*k].x, SR[2*k].y, SR[2*k+1].x, SR[2*k+1].y);
    }
}

extern "C" void kernel_launch(void* const* d_in, const int* in_sizes, int n_in,
                              void* d_out, int out_size, void* d_ws, size_t ws_size,
                              hipStream_t stream)
{
    const float* theta     = (const float*)d_in[0];
    const int*   positions = (const int*)d_in[1];
    float*       out       = (float*)d_out;
    const int B = in_sizes[1];   // 4096

    pqc_sim_kernel<<<B / WAVES_PER_BLOCK, 64 * WAVES_PER_BLOCK, 0, stream>>>(
        theta, positions, out);
}

// Round 5
// 90.506 us; speedup vs baseline: 1.2442x; 1.2442x over previous
//
#include <hip/hip_runtime.h>
#include <math.h>

#define N_QUBITS 11
#define N_LAYERS 2
#define DIM 2048
#define N_GATES 22
#define ROW 36   // padded LDS row stride in floats (32 data + 4 pad: keeps b128
                 // alignment, makes transpose reads 2-way bank aliased = free)

typedef float v2f __attribute__((ext_vector_type(2)));
static __device__ __forceinline__ v2f splat(float s) { return (v2f){s, s}; }

// ---------------------------------------------------------------------------
// One wave (64 lanes) per batch element; state in VGPRs as packed v2f
// (SR[k]/SI[k] hold amps 2k,2k+1; lane L owns amps L*32..L*32+31).
//
// Per layer, instead of 6 shuffle-exchange gates (DS-pipe bound, round 3):
//   arrangement A (identity): qubits 0-4 local  -> 5 register butterflies
//   LDS trip "swap":  storage bits [0:4]<->[5:9] (32x32 transpose)
//   arrangement B: qubits 5-9 local             -> 5 register butterflies
//   qubit 10 = lane bit 5 in both arrangements  -> 1 shfl_xor(32) gate
//   LDS trip "cnot": swap-back composed with the fused CNOT-ladder
//                    permutation src = j ^ (j<<1)  (proven in round 3)
// Layer 1 shortcut: phase A on |0..0> has closed form; the post-swap B state
// is simply S[0].x = prod_q U_q[bit_q(L)][0] on lanes 0..31 -> build directly.
//
// Single-wave workgroups: per-wave DS ops are processed in order, so the
// write->read->write sequences need no __syncthreads().
//
// amdgpu_waves_per_eu(4,4): pins the allocator to a 128-VGPR budget. Without
// the max pin, LLVM targets 8 waves/EU (64 VGPRs) and SPILLS the state to
// scratch (rounds 2 & 4: VGPR_Count=64 + GB-scale scratch traffic).
// ---------------------------------------------------------------------------

static __device__ __forceinline__
void apply5(v2f (&SR)[16], v2f (&SI)[16], const float (*G)[8], int gbase)
{
    {   // local bit 0: intra-v2f butterfly (packed splat form, validated r4)
        const float* g = G[gbase];
        const v2f C0r = {g[0], g[4]}, C0i = {g[1], g[5]};
        const v2f C1r = {g[2], g[6]}, C1i = {g[3], g[7]};
        #pragma unroll
        for (int k = 0; k < 16; ++k) {
            const v2f rx = splat(SR[k].x), ry = splat(SR[k].y);
            const v2f ix = splat(SI[k].x), iy = splat(SI[k].y);
            SR[k] = C0r * rx - C0i * ix + C1r * ry - C1i * iy;
            SI[k] = C0r * ix + C0i * rx + C1r * iy + C1i * ry;
        }
    }
    #pragma unroll
    for (int t = 1; t < 5; ++t) {   // local bits 1..4: cross-register packed
        const float* g = G[gbase + t];
        const v2f u00r = splat(g[0]), u00i = splat(g[1]);
        const v2f u01r = splat(g[2]), u01i = splat(g[3]);
        const v2f u10r = splat(g[4]), u10i = splat(g[5]);
        const v2f u11r = splat(g[6]), u11i = splat(g[7]);
        const int h = 1 << (t - 1);
        #pragma unroll
        for (int s = 0; s < 8; ++s) {
            const int k0 = ((s >> (t - 1)) << t) | (s & (h - 1));
            const int k1 = k0 + h;
            const v2f ar = SR[k0], ai = SI[k0];
            const v2f br = SR[k1], bi = SI[k1];
            SR[k0] = u00r * ar - u00i * ai + u01r * br - u01i * bi;
            SI[k0] = u00r * ai + u00i * ar + u01r * bi + u01i * br;
            SR[k1] = u10r * ar - u10i * ai + u11r * br - u11i * bi;
            SI[k1] = u10r * ai + u10i * ar + u11r * bi + u11i * br;
        }
    }
}

static __device__ __forceinline__
void lane_gate_q10(v2f (&SR)[16], v2f (&SI)[16], const float* g, int L)
{
    const int bit = (L >> 5) & 1;
    const v2f csr = splat(bit ? g[6] : g[0]), csi = splat(bit ? g[7] : g[1]);
    const v2f cpr = splat(bit ? g[4] : g[2]), cpi = splat(bit ? g[5] : g[3]);
    #pragma unroll
    for (int k = 0; k < 16; ++k) {
        const double dr = __builtin_bit_cast(double, SR[k]);
        const double di = __builtin_bit_cast(double, SI[k]);
        const v2f pr = __builtin_bit_cast(v2f, __shfl_xor(dr, 32));
        const v2f pi = __builtin_bit_cast(v2f, __shfl_xor(di, 32));
        const v2f ar = SR[k], ai = SI[k];
        SR[k] = csr * ar - csi * ai + cpr * pr - cpi * pi;
        SI[k] = csr * ai + csi * ar + cpr * pi + cpi * pr;
    }
}

// Write lane's 32 floats row-major (b128 x8) into padded LDS rows.
static __device__ __forceinline__
void write_rows(float* buf, const v2f (&S)[16], int L)
{
    #pragma unroll
    for (int k = 0; k < 8; ++k) {
        *(float4*)&buf[L * ROW + 4 * k] =
            make_float4(S[2*k].x, S[2*k].y, S[2*k+1].x, S[2*k+1].y);
    }
}

// Trip A->B: dest (L',n') <- A(lane = n' | (L'&32), reg = L'&31).
// For fixed n', banks = (4*srcLane + (L'&31)) % 32: 2-way aliased = free.
static __device__ __forceinline__
void read_swap(const float* buf, v2f (&S)[16], int L)
{
    const int rb = L & 32;    // src lane bit 5
    const int rr = L & 31;    // src reg
    #pragma unroll
    for (int t = 0; t < 16; ++t) {
        const float a0 = buf[(2*t     | rb) * ROW + rr];
        const float a1 = buf[((2*t+1) | rb) * ROW + rr];
        S[t] = (v2f){a0, a1};
    }
}

// Trip B->A composed with fused CNOT ladder: final storage j holds amp with
// qubit-index f(j) = (j ^ (j<<1)) & 2047, read from B at
//   srcLane = (f&31) | (bit10(f)<<5),  srcReg = f[5:9].
// With j = L*32+n:  f&31 = (n^(n<<1))&31,  f[5:9] = ((L^(L<<1))&31) ^ (n>>4),
// bit10(f) = (L>>5)^(L>>4) & 1.   (index identities verified by hand: j=0,1,
// 16,32,1024 all map correctly.)
static __device__ __forceinline__
void read_cnot(const float* buf, v2f (&S)[16], int L)
{
    const int gl      = (L ^ (L << 1)) & 31;
    const int lane_or = ((((L >> 5) ^ (L >> 4)) & 1) << 5);
    #pragma unroll
    for (int t = 0; t < 16; ++t) {
        const int n0 = 2 * t, n1 = 2 * t + 1;
        const int f0 = (n0 ^ (n0 << 1)) & 31;
        const int f1 = (n1 ^ (n1 << 1)) & 31;
        const int reg = gl ^ (n0 >> 4);          // n>>4 equal within the pair
        const float a0 = buf[(f0 | lane_or) * ROW + reg];
        const float a1 = buf[(f1 | lane_or) * ROW + reg];
        S[t] = (v2f){a0, a1};
    }
}

__global__ __launch_bounds__(64) __attribute__((amdgpu_waves_per_eu(4, 4)))
void pqc_sim_kernel(const float* __restrict__ theta,
                    const int* __restrict__ positions,
                    float* __restrict__ out)
{
    __shared__ float G[N_GATES][8];     // 704 B
    __shared__ float buf[64 * ROW];     // 9216 B  (total 9.9 KB -> 16 wg/CU)

    const int b   = blockIdx.x;
    const int L   = threadIdx.x;
    const int pos = positions[b];

    // ---- Gate precompute: U = Rz(g)*Ry(b)*Rx(a), angles*0.5 (validated) ----
    if (L < N_GATES) {
        const int l = L / N_QUBITS;
        const int q = L % N_QUBITS;
        const float* th = theta + (((size_t)pos * N_LAYERS + l) * (3 * N_QUBITS)) + 3 * q;
        const float a  = th[0] * 0.5f;
        const float bb = th[1] * 0.5f;
        const float g  = th[2] * 0.5f;
        float sa, ca, sb, cb, sg, cg;
        sincosf(a,  &sa, &ca);
        sincosf(bb, &sb, &cb);
        sincosf(g,  &sg, &cg);
        const float m00r =  cb * ca, m00i =  sb * sa;
        const float m01r = -sb * ca, m01i = -cb * sa;
        const float m10r =  sb * ca, m10i = -cb * sa;
        const float m11r =  cb * ca, m11i = -sb * sa;
        G[L][0] = m00r * cg + m00i * sg;  G[L][1] = m00i * cg - m00r * sg;
        G[L][2] = m01r * cg + m01i * sg;  G[L][3] = m01i * cg - m01r * sg;
        G[L][4] = m10r * cg - m10i * sg;  G[L][5] = m10i * cg + m10r * sg;
        G[L][6] = m11r * cg - m11i * sg;  G[L][7] = m11i * cg + m11r * sg;
    }
    __syncthreads();   // one barrier total (gate table visibility)

    v2f SR[16], SI[16];
    #pragma unroll
    for (int k = 0; k < 16; ++k) { SR[k] = (v2f){0.f, 0.f}; SI[k] = (v2f){0.f, 0.f}; }

    // ================= Layer 1 =================
    // Closed-form phase A on |0>, directly in arrangement B:
    // B-state: S[0].x on lane m (<32) = prod_{q=0..4} U_q[bit_q(m)][0].
    {
        const int m = L & 31;
        float cr = G[0][(m & 1) ? 4 : 0];
        float ci = G[0][(m & 1) ? 5 : 1];
        #pragma unroll
        for (int q = 1; q < 5; ++q) {
            const int bq = (m >> q) & 1;
            const float gr = G[q][bq ? 4 : 0];
            const float gi = G[q][bq ? 5 : 1];
            const float tr = cr * gr - ci * gi;
            ci = cr * gi + ci * gr;
            cr = tr;
        }
        if (L & 32) { cr = 0.f; ci = 0.f; }
        SR[0].x = cr;
        SI[0].x = ci;
    }
    apply5(SR, SI, G, 5);               // qubits 5..9 (local in B)
    lane_gate_q10(SR, SI, G[10], L);    // qubit 10 (lane bit 5)
    write_rows(buf, SR, L);  read_cnot(buf, SR, L);   // CNOT + back to A
    write_rows(buf, SI, L);  read_cnot(buf, SI, L);

    // ================= Layer 2 =================
    apply5(SR, SI, G, 11);              // qubits 0..4 (local in A)
    write_rows(buf, SR, L);  read_swap(buf, SR, L);   // A -> B
    write_rows(buf, SI, L);  read_swap(buf, SI, L);
    apply5(SR, SI, G, 16);              // qubits 5..9 (local in B)
    lane_gate_q10(SR, SI, G[21], L);    // qubit 10
    write_rows(buf, SR, L);  read_cnot(buf, SR, L);   // CNOT + back to A
    write_rows(buf, SI, L);  read_cnot(buf, SI, L);

    // ---- Epilogue: real part; lane L owns 32 consecutive floats ----
    float* orow = out + (size_t)b * DIM + L * 32;
    #pragma unroll
    for (int k = 0; k < 8; ++k) {
        *(float4*)(orow + 4 * k) =
            make_float4(SR[2*k].x, SR[2*k].y, SR[2*k+1].x, SR[2*k+1].y);
    }
}

extern "C" void kernel_launch(void* const* d_in, const int* in_sizes, int n_in,
                              void* d_out, int out_size, void* d_ws, size_t ws_size,
                              hipStream_t stream)
{
    const float* theta     = (const float*)d_in[0];
    const int*   positions = (const int*)d_in[1];
    float*       out       = (float*)d_out;
    const int B = in_sizes[1];   // 4096

    pqc_sim_kernel<<<B, 64, 0, stream>>>(theta, positions, out);
}

// Round 6
// 89.954 us; speedup vs baseline: 1.2518x; 1.0061x over previous
//
#include <hip/hip_runtime.h>
#include <math.h>

#define N_QUBITS 11
#define N_LAYERS 2
#define DIM 2048
#define N_GATES 22
#define ROW 36   // padded LDS row stride (32 data + 4): b128-aligned, 2-way-free reads

typedef float v2f __attribute__((ext_vector_type(2)));
static __device__ __forceinline__ v2f splat(float s) { return (v2f){s, s}; }

// ---------------------------------------------------------------------------
// One wave per batch element; state in VGPRs as packed v2f (SR[k]/SI[k] hold
// amps 2k,2k+1; lane L owns amps L*32..L*32+31).
//
// LAYER 1 IS CLOSED-FORM: all layer-1 gates act on |0..0>, so the pre-CNOT
// state is a tensor product amp(i) = prod_q U_q[i_q][0]. Composed with the
// fused CNOT permutation src = j^(j<<1) (validated R3/R5), layer-1 output:
//   S[j] = prod_{q=0..10} c_q(b_q),  b = j^(j<<1),  c_q(x) = U_q[x][0]
// Built per-lane in registers: 5-level tensor doubling over m = b&31 with
// compile-time position map n(m) = prefix-xor(m), times a lane factor from
// bits of L^(L>>1). No LDS trip, no q10 shuffle, no apply5 for layer 1.
//
// Layer 2 (validated R5): apply5 on qubits 0-4 (A-local) -> LDS transpose
// trip (A->B) -> apply5 on qubits 5-9 (B-local) -> q10 via shfl_xor(32) ->
// final CNOT trip for SR ONLY (output is the real part; SI trip is dead).
//
// Single-wave workgroups: per-wave DS ordering makes write->read safe with
// no barriers. amdgpu_waves_per_eu(4,4) pins a 128-VGPR budget (without the
// max pin LLVM targets 8 waves/EU = 64 VGPRs and spills the state: R2/R4).
// ---------------------------------------------------------------------------

static __device__ __forceinline__ int nofm(int m) {
    // n(m): n_j = m_0^...^m_j (prefix xor) -- inverse of m = (n^(n<<1))&31
    int n = 0, p = 0;
    #pragma unroll
    for (int q = 0; q < 5; ++q) { p ^= (m >> q) & 1; n |= p << q; }
    return n;
}

static __device__ __forceinline__ float getS(const v2f (&S)[16], int n) {
    return (n & 1) ? S[n >> 1].y : S[n >> 1].x;
}
static __device__ __forceinline__ void setS(v2f (&S)[16], int n, float v) {
    if (n & 1) S[n >> 1].y = v; else S[n >> 1].x = v;
}

static __device__ __forceinline__
void apply5(v2f (&SR)[16], v2f (&SI)[16], const float (*G)[8], int gbase)
{
    {   // local bit 0: intra-v2f butterfly (packed splat form)
        const float4 gA = *(const float4*)&G[gbase][0];
        const float4 gB = *(const float4*)&G[gbase][4];
        const v2f C0r = {gA.x, gB.x}, C0i = {gA.y, gB.y};
        const v2f C1r = {gA.z, gB.z}, C1i = {gA.w, gB.w};
        #pragma unroll
        for (int k = 0; k < 16; ++k) {
            const v2f rx = splat(SR[k].x), ry = splat(SR[k].y);
            const v2f ix = splat(SI[k].x), iy = splat(SI[k].y);
            SR[k] = C0r * rx - C0i * ix + C1r * ry - C1i * iy;
            SI[k] = C0r * ix + C0i * rx + C1r * iy + C1i * ry;
        }
    }
    #pragma unroll
    for (int t = 1; t < 5; ++t) {   // local bits 1..4: cross-register packed
        const float4 gA = *(const float4*)&G[gbase + t][0];
        const float4 gB = *(const float4*)&G[gbase + t][4];
        const v2f u00r = splat(gA.x), u00i = splat(gA.y);
        const v2f u01r = splat(gA.z), u01i = splat(gA.w);
        const v2f u10r = splat(gB.x), u10i = splat(gB.y);
        const v2f u11r = splat(gB.z), u11i = splat(gB.w);
        const int h = 1 << (t - 1);
        #pragma unroll
        for (int s = 0; s < 8; ++s) {
            const int k0 = ((s >> (t - 1)) << t) | (s & (h - 1));
            const int k1 = k0 + h;
            const v2f ar = SR[k0], ai = SI[k0];
            const v2f br = SR[k1], bi = SI[k1];
            SR[k0] = u00r * ar - u00i * ai + u01r * br - u01i * bi;
            SI[k0] = u00r * ai + u00i * ar + u01r * bi + u01i * br;
            SR[k1] = u10r * ar - u10i * ai + u11r * br - u11i * bi;
            SI[k1] = u10r * ai + u10i * ar + u11r * bi + u11i * br;
        }
    }
}

static __device__ __forceinline__
void lane_gate_q10(v2f (&SR)[16], v2f (&SI)[16], const float* g, int L)
{
    const int bit = (L >> 5) & 1;
    const v2f csr = splat(bit ? g[6] : g[0]), csi = splat(bit ? g[7] : g[1]);
    const v2f cpr = splat(bit ? g[4] : g[2]), cpi = splat(bit ? g[5] : g[3]);
    #pragma unroll
    for (int k = 0; k < 16; ++k) {
        const double dr = __builtin_bit_cast(double, SR[k]);
        const double di = __builtin_bit_cast(double, SI[k]);
        const v2f pr = __builtin_bit_cast(v2f, __shfl_xor(dr, 32));
        const v2f pi = __builtin_bit_cast(v2f, __shfl_xor(di, 32));
        const v2f ar = SR[k], ai = SI[k];
        SR[k] = csr * ar - csi * ai + cpr * pr - cpi * pi;
        SI[k] = csr * ai + csi * ar + cpr * pi + cpi * pr;
    }
}

static __device__ __forceinline__
void write_rows(float* buf, const v2f (&S)[16], int L)
{
    #pragma unroll
    for (int k = 0; k < 8; ++k) {
        *(float4*)&buf[L * ROW + 4 * k] =
            make_float4(S[2*k].x, S[2*k].y, S[2*k+1].x, S[2*k+1].y);
    }
}

// Trip A->B: dest (L',n') <- A(lane = n' | (L'&32), reg = L'&31).
static __device__ __forceinline__
void read_swap(const float* buf, v2f (&S)[16], int L)
{
    const int rb = L & 32;
    const int rr = L & 31;
    #pragma unroll
    for (int t = 0; t < 16; ++t) {
        const float a0 = buf[(2*t     | rb) * ROW + rr];
        const float a1 = buf[((2*t+1) | rb) * ROW + rr];
        S[t] = (v2f){a0, a1};
    }
}

// Trip B->A composed with fused CNOT ladder (validated R5).
static __device__ __forceinline__
void read_cnot(const float* buf, v2f (&S)[16], int L)
{
    const int gl      = (L ^ (L << 1)) & 31;
    const int lane_or = ((((L >> 5) ^ (L >> 4)) & 1) << 5);
    #pragma unroll
    for (int t = 0; t < 16; ++t) {
        const int n0 = 2 * t, n1 = 2 * t + 1;
        const int f0 = (n0 ^ (n0 << 1)) & 31;
        const int f1 = (n1 ^ (n1 << 1)) & 31;
        const int reg = gl ^ (n0 >> 4);
        const float a0 = buf[(f0 | lane_or) * ROW + reg];
        const float a1 = buf[(f1 | lane_or) * ROW + reg];
        S[t] = (v2f){a0, a1};
    }
}

__global__ __launch_bounds__(64) __attribute__((amdgpu_waves_per_eu(4, 4)))
void pqc_sim_kernel(const float* __restrict__ theta,
                    const int* __restrict__ positions,
                    float* __restrict__ out)
{
    __shared__ float G[N_GATES][8];     // 704 B
    __shared__ float buf[64 * ROW];     // 9216 B

    const int b   = blockIdx.x;
    const int L   = threadIdx.x;
    const int pos = positions[b];

    // ---- Gate precompute: U = Rz(g)*Ry(b)*Rx(a), angles*0.5 (validated) ----
    if (L < N_GATES) {
        const int l = L / N_QUBITS;
        const int q = L % N_QUBITS;
        const float* th = theta + (((size_t)pos * N_LAYERS + l) * (3 * N_QUBITS)) + 3 * q;
        const float a  = th[0] * 0.5f;
        const float bb = th[1] * 0.5f;
        const float g  = th[2] * 0.5f;
        float sa, ca, sb, cb, sg, cg;
        sincosf(a,  &sa, &ca);
        sincosf(bb, &sb, &cb);
        sincosf(g,  &sg, &cg);
        const float m00r =  cb * ca, m00i =  sb * sa;
        const float m01r = -sb * ca, m01i = -cb * sa;
        const float m10r =  sb * ca, m10i = -cb * sa;
        const float m11r =  cb * ca, m11i = -sb * sa;
        G[L][0] = m00r * cg + m00i * sg;  G[L][1] = m00i * cg - m00r * sg;
        G[L][2] = m01r * cg + m01i * sg;  G[L][3] = m01i * cg - m01r * sg;
        G[L][4] = m10r * cg - m10i * sg;  G[L][5] = m10i * cg + m10r * sg;
        G[L][6] = m11r * cg - m11i * sg;  G[L][7] = m11i * cg + m11r * sg;
    }
    __syncthreads();

    v2f SR[16], SI[16];

    // ================= Layer 1: closed-form product state =================
    // S[j] = prod_q c_q(b_q), b = j^(j<<1). j = L*32+n:
    //   q=0..4  : b_q from m(n) = (n^(n<<1))&31  (doubling over m-bits)
    //   q=5     : b_5 = L_0 ^ n_4                (two lane factors F0/F1)
    //   q=6..10 : b_q = bit (q-6) of (L ^ (L>>1)) (per-lane chain)
    {
        // 5-level tensor doubling: T[m] = prod_{q<5} c_q(m_q), stored at n(m).
        float car0[5], cai0[5], car1[5], cai1[5];
        #pragma unroll
        for (int q = 0; q < 5; ++q) {
            car0[q] = G[q][0]; cai0[q] = G[q][1];   // c_q(0)
            car1[q] = G[q][4]; cai1[q] = G[q][5];   // c_q(1)
        }
        setS(SR, nofm(0), car0[0]);  setS(SI, nofm(0), cai0[0]);
        setS(SR, nofm(1), car1[0]);  setS(SI, nofm(1), cai1[0]);
        #pragma unroll
        for (int q = 1; q < 5; ++q) {
            #pragma unroll
            for (int m = 0; m < (1 << q); ++m) {
                const int ns = nofm(m);
                const int nd = nofm(m | (1 << q));
                const float ar = getS(SR, ns), ai = getS(SI, ns);
                setS(SR, nd, ar * car1[q] - ai * cai1[q]);
                setS(SI, nd, ar * cai1[q] + ai * car1[q]);
                setS(SR, ns, ar * car0[q] - ai * cai0[q]);
                setS(SI, ns, ar * cai0[q] + ai * car0[q]);
            }
        }

        // Lane factor PL = prod_{k=0..4} c_{6+k}(x_k), x = L^(L>>1)
        const int x = L ^ (L >> 1);
        float plr, pli;
        {
            const int bq = x & 1;
            plr = bq ? G[6][4] : G[6][0];
            pli = bq ? G[6][5] : G[6][1];
        }
        #pragma unroll
        for (int k = 1; k < 5; ++k) {
            const int bq = (x >> k) & 1;
            const float cr = bq ? G[6 + k][4] : G[6 + k][0];
            const float ci = bq ? G[6 + k][5] : G[6 + k][1];
            const float tr = plr * cr - pli * ci;
            pli = plr * ci + pli * cr;
            plr = tr;
        }
        // F0 = PL*c5(L_0) (for n_4=0), F1 = PL*c5(L_0^1) (for n_4=1)
        const int l0 = L & 1;
        const float c5ar = l0 ? G[5][4] : G[5][0];
        const float c5ai = l0 ? G[5][5] : G[5][1];
        const float c5br = l0 ? G[5][0] : G[5][4];
        const float c5bi = l0 ? G[5][1] : G[5][5];
        const float F0r = plr * c5ar - pli * c5ai, F0i = plr * c5ai + pli * c5ar;
        const float F1r = plr * c5br - pli * c5bi, F1i = plr * c5bi + pli * c5br;

        #pragma unroll
        for (int n = 0; n < 32; ++n) {
            const float fr = (n & 16) ? F1r : F0r;
            const float fi = (n & 16) ? F1i : F0i;
            const float ar = getS(SR, n), ai = getS(SI, n);
            setS(SR, n, ar * fr - ai * fi);
            setS(SI, n, ar * fi + ai * fr);
        }
    }

    // ================= Layer 2 (validated R5 structure) =================
    apply5(SR, SI, G, 11);              // qubits 0..4 (A-local)
    write_rows(buf, SR, L);  read_swap(buf, SR, L);   // A -> B
    write_rows(buf, SI, L);  read_swap(buf, SI, L);
    apply5(SR, SI, G, 16);              // qubits 5..9 (B-local)
    lane_gate_q10(SR, SI, G[21], L);    // qubit 10
    write_rows(buf, SR, L);  read_cnot(buf, SR, L);   // CNOT + back to A
    // (SI's final trip is dead: output is the real part only)

    // ---- Epilogue: real part; lane L owns 32 consecutive floats ----
    float* orow = out + (size_t)b * DIM + L * 32;
    #pragma unroll
    for (int k = 0; k < 8; ++k) {
        *(float4*)(orow + 4 * k) =
            make_float4(SR[2*k].x, SR[2*k].y, SR[2*k+1].x, SR[2*k+1].y);
    }
}

extern "C" void kernel_launch(void* const* d_in, const int* in_sizes, int n_in,
                              void* d_out, int out_size, void* d_ws, size_t ws_size,
                              hipStream_t stream)
{
    const float* theta     = (const float*)d_in[0];
    const int*   positions = (const int*)d_in[1];
    float*       out       = (float*)d_out;
    const int B = in_sizes[1];   // 4096

    pqc_sim_kernel<<<B, 64, 0, stream>>>(theta, positions, out);
}

// Round 7
// 86.387 us; speedup vs baseline: 1.3035x; 1.0413x over previous
//
#include <hip/hip_runtime.h>
#include <math.h>

#define N_QUBITS 11
#define DIM 2048

typedef float v2f __attribute__((ext_vector_type(2)));
static __device__ __forceinline__ v2f splat(float s) { return (v2f){s, s}; }

// ---------------------------------------------------------------------------
// TWO waves per batch element (128-thread WG). Arrangement A: amplitude
// j = n + 16*L + 1024*w  (n = 4 local bits in regs, L = 6 lane bits, w = wave
// bit = qubit 10). State per lane: 16 complex = v2f SR[8] + SI[8] = 32 VGPRs,
// peak pressure ~60 -- genuinely under the 64-VGPR clamp this compiler
// enforces whenever pressure exceeds 64 (R2/R4/R6 all spilled at exactly
// VGPR_Count=64 under three different attribute spellings). Bonus: 8192
// waves -> 32 waves/CU (8/SIMD) vs 16 before.
//
// Layer 1 closed form (R6-validated): post-ladder S[j] = prod_q c_q(f_q),
// f = j ^ (j<<1), c_q(x) = U1_q[x][0]. f bits for j=(w,L,n):
//   f[0:3]=(n^(n<<1))&15, f4=L0^n3, f(5+t)=L(t+1)^Lt, f10=w^L5.
// Layer 2: apply4(q0-3 local) -> trip1 (INTRA-wave LDS transpose: storage
// bits [0:3]<->[4:7]; per-wave DS ordering => no barriers) -> apply4(q4-7)
// -> shfl_xor gates q8 (mask16), q9 (mask32) -> trip2: stage B-state in two
// passes (wave0 then wave1) and fold qubit-10 gate (cross-wave) + CNOT
// ladder + B->A remap into the reads; produce real part only.
//
// LDS: G2 352B + C1 176B + buf 8704B (2x64x17 f32, odd stride => all
// staging reads/writes 2-way bank aliased = free) = 9.2 KB -> 16 WG/CU.
// ---------------------------------------------------------------------------

static __device__ __forceinline__ float getS(const v2f (&S)[8], int n) {
    return (n & 1) ? S[n >> 1].y : S[n >> 1].x;
}
static __device__ __forceinline__ void setS(v2f (&S)[8], int n, float v) {
    if (n & 1) S[n >> 1].y = v; else S[n >> 1].x = v;
}
static __device__ __forceinline__ int nofm4(int m) {
    // 4-bit prefix-xor: inverse of m = (n ^ (n<<1)) & 15
    int n = 0, p = 0;
    #pragma unroll
    for (int q = 0; q < 4; ++q) { p ^= (m >> q) & 1; n |= p << q; }
    return n;
}

static __device__ __forceinline__
void apply4(v2f (&SR)[8], v2f (&SI)[8], const float (*G)[8], int gbase)
{
    {   // slot bit 0: intra-v2f butterfly (packed splat form, R4/R5-validated)
        const float4 gA = *(const float4*)&G[gbase][0];
        const float4 gB = *(const float4*)&G[gbase][4];
        const v2f C0r = {gA.x, gB.x}, C0i = {gA.y, gB.y};
        const v2f C1r = {gA.z, gB.z}, C1i = {gA.w, gB.w};
        #pragma unroll
        for (int k = 0; k < 8; ++k) {
            const v2f rx = splat(SR[k].x), ry = splat(SR[k].y);
            const v2f ix = splat(SI[k].x), iy = splat(SI[k].y);
            SR[k] = C0r * rx - C0i * ix + C1r * ry - C1i * iy;
            SI[k] = C0r * ix + C0i * rx + C1r * iy + C1i * ry;
        }
    }
    #pragma unroll
    for (int t = 1; t < 4; ++t) {   // slot bits 1..3: cross-register packed
        const float4 gA = *(const float4*)&G[gbase + t][0];
        const float4 gB = *(const float4*)&G[gbase + t][4];
        const v2f u00r = splat(gA.x), u00i = splat(gA.y);
        const v2f u01r = splat(gA.z), u01i = splat(gA.w);
        const v2f u10r = splat(gB.x), u10i = splat(gB.y);
        const v2f u11r = splat(gB.z), u11i = splat(gB.w);
        const int h = 1 << (t - 1);
        #pragma unroll
        for (int s = 0; s < 4; ++s) {
            const int k0 = ((s >> (t - 1)) << t) | (s & (h - 1));
            const int k1 = k0 + h;
            const v2f ar = SR[k0], ai = SI[k0];
            const v2f br = SR[k1], bi = SI[k1];
            SR[k0] = u00r * ar - u00i * ai + u01r * br - u01i * bi;
            SI[k0] = u00r * ai + u00i * ar + u01r * bi + u01i * br;
            SR[k1] = u10r * ar - u10i * ai + u11r * br - u11i * bi;
            SI[k1] = u10r * ai + u10i * ar + u11r * bi + u11i * br;
        }
    }
}

static __device__ __forceinline__
void shfl_gate(v2f (&SR)[8], v2f (&SI)[8], const float* g, int bit, int mask)
{
    const v2f csr = splat(bit ? g[6] : g[0]), csi = splat(bit ? g[7] : g[1]);
    const v2f cpr = splat(bit ? g[4] : g[2]), cpi = splat(bit ? g[5] : g[3]);
    #pragma unroll
    for (int k = 0; k < 8; ++k) {
        const double dr = __builtin_bit_cast(double, SR[k]);
        const double di = __builtin_bit_cast(double, SI[k]);
        const v2f pr = __builtin_bit_cast(v2f, __shfl_xor(dr, mask));
        const v2f pi = __builtin_bit_cast(v2f, __shfl_xor(di, mask));
        const v2f ar = SR[k], ai = SI[k];
        SR[k] = csr * ar - csi * ai + cpr * pr - cpi * pi;
        SI[k] = csr * ai + csi * ar + cpr * pi + cpi * pr;
    }
}

__global__ __launch_bounds__(128)
void pqc_sim_kernel(const float* __restrict__ theta,
                    const int* __restrict__ positions,
                    float* __restrict__ out)
{
    __shared__ float G2[N_QUBITS][8];   // layer-2 gates, full 2x2 complex
    __shared__ float C1[N_QUBITS][4];   // layer-1 col0: re0, im0, re1, im1
    __shared__ float buf[2176];         // 2 regions x 64 rows x 17 floats

    const int t = threadIdx.x;
    const int w = t >> 6;               // wave = qubit-10 bit
    const int L = t & 63;
    const int b = blockIdx.x;
    const int pos = positions[b];

    // ---- Gate precompute: U = Rz(g)*Ry(b)*Rx(a), angles*0.5 (validated) ----
    if (t < 22) {
        const int l = t / N_QUBITS;
        const int q = t % N_QUBITS;
        const float* th = theta + (((size_t)pos * 2 + l) * (3 * N_QUBITS)) + 3 * q;
        const float a  = th[0] * 0.5f;
        const float bb = th[1] * 0.5f;
        const float g  = th[2] * 0.5f;
        float sa, ca, sb, cb, sg, cg;
        sincosf(a,  &sa, &ca);
        sincosf(bb, &sb, &cb);
        sincosf(g,  &sg, &cg);
        const float m00r =  cb * ca, m00i =  sb * sa;
        const float m01r = -sb * ca, m01i = -cb * sa;
        const float m10r =  sb * ca, m10i = -cb * sa;
        const float m11r =  cb * ca, m11i = -sb * sa;
        const float u00r = m00r * cg + m00i * sg, u00i = m00i * cg - m00r * sg;
        const float u01r = m01r * cg + m01i * sg, u01i = m01i * cg - m01r * sg;
        const float u10r = m10r * cg - m10i * sg, u10i = m10i * cg + m10r * sg;
        const float u11r = m11r * cg - m11i * sg, u11i = m11i * cg + m11r * sg;
        if (l) {
            G2[q][0] = u00r; G2[q][1] = u00i; G2[q][2] = u01r; G2[q][3] = u01i;
            G2[q][4] = u10r; G2[q][5] = u10i; G2[q][6] = u11r; G2[q][7] = u11i;
        } else {
            C1[q][0] = u00r; C1[q][1] = u00i;   // c_q(0) = U[0][0]
            C1[q][2] = u10r; C1[q][3] = u10i;   // c_q(1) = U[1][0]
        }
    }
    __syncthreads();

    v2f SR[8], SI[8];

    // ================= Layer 1: closed-form product (R6-validated) ========
    {
        // 4-bit doubling over f-part m, stored at slot nofm4(m)
        setS(SR, 0,  C1[0][0]);  setS(SI, 0,  C1[0][1]);   // nofm4(0)=0
        setS(SR, 15, C1[0][2]);  setS(SI, 15, C1[0][3]);   // nofm4(1)=15
        #pragma unroll
        for (int q = 1; q < 4; ++q) {
            const float c0r = C1[q][0], c0i = C1[q][1];
            const float c1r = C1[q][2], c1i = C1[q][3];
            #pragma unroll
            for (int m = 0; m < (1 << q); ++m) {
                const int ns = nofm4(m), nd = nofm4(m | (1 << q));
                const float ar = getS(SR, ns), ai = getS(SI, ns);
                setS(SR, nd, ar * c1r - ai * c1i);
                setS(SI, nd, ar * c1i + ai * c1r);
                setS(SR, ns, ar * c0r - ai * c0i);
                setS(SI, ns, ar * c0i + ai * c0r);
            }
        }
        // lane/wave factor: f(5+t) = L(t+1)^Lt -> bits of (L^(L<<1))>>1;
        // f10 = w ^ L5
        const int z = (L ^ (L << 1)) >> 1;
        float plr, pli;
        { const int o = (z & 1) ? 2 : 0; plr = C1[5][o]; pli = C1[5][o + 1]; }
        #pragma unroll
        for (int k = 1; k < 5; ++k) {
            const int o = ((z >> k) & 1) ? 2 : 0;
            const float cr = C1[5 + k][o], ci = C1[5 + k][o + 1];
            const float tr = plr * cr - pli * ci;
            pli = plr * ci + pli * cr;  plr = tr;
        }
        {
            const int o = (w ^ ((L >> 5) & 1)) ? 2 : 0;
            const float cr = C1[10][o], ci = C1[10][o + 1];
            const float tr = plr * cr - pli * ci;
            pli = plr * ci + pli * cr;  plr = tr;
        }
        // edge factor f4 = L0 ^ n3
        const int l0 = L & 1;
        const float e0r = C1[4][l0 ? 2 : 0], e0i = C1[4][l0 ? 3 : 1];
        const float e1r = C1[4][l0 ? 0 : 2], e1i = C1[4][l0 ? 1 : 3];
        const float F0r = plr * e0r - pli * e0i, F0i = plr * e0i + pli * e0r;
        const float F1r = plr * e1r - pli * e1i, F1i = plr * e1i + pli * e1r;
        #pragma unroll
        for (int k = 0; k < 8; ++k) {
            const v2f fr = splat(k < 4 ? F0r : F1r);
            const v2f fi = splat(k < 4 ? F0i : F1i);
            const v2f r = SR[k], i = SI[k];
            SR[k] = r * fr - i * fi;
            SI[k] = r * fi + i * fr;
        }
    }

    // ================= Layer 2 ============================================
    apply4(SR, SI, G2, 0);              // qubits 0..3 (local slot bits)

    // ---- Trip1: storage bits [0:3]<->[4:7] (intra-wave, no barriers) ----
    {
        float* reg = buf + w * 1088;    // own wave's 64x17 region
        const int hi = L & 48;          // src row high bits (L4,L5 preserved)
        const int cs = L & 15;          // src column
        #pragma unroll
        for (int n = 0; n < 16; ++n) reg[L * 17 + n] = getS(SR, n);
        #pragma unroll
        for (int n = 0; n < 16; ++n) setS(SR, n, reg[(n + hi) * 17 + cs]);
        #pragma unroll
        for (int n = 0; n < 16; ++n) reg[L * 17 + n] = getS(SI, n);
        #pragma unroll
        for (int n = 0; n < 16; ++n) setS(SI, n, reg[(n + hi) * 17 + cs]);
    }

    apply4(SR, SI, G2, 4);              // qubits 4..7 (slot bits in B)
    shfl_gate(SR, SI, G2[8], (L >> 4) & 1, 16);   // qubit 8 = lane bit 4
    shfl_gate(SR, SI, G2[9], (L >> 5) & 1, 32);   // qubit 9 = lane bit 5

    // ---- Trip2: qubit-10 gate + CNOT ladder + B->A, real part only ------
    // dest j=(w,L,n): f = j^(j<<1); source amps f&~1024 (pass 0, wave-0
    // rows) and f|1024 (pass 1, wave-1 rows) at B-location:
    //   row = ((n^(n<<1))&15) | ((L^(L<<1))&48),  col = ((L^(L<<1))&15)^n3
    // out = Re( U21[f10][0]*amp0 + U21[f10][1]*amp1 ),  f10 = w^L5.
    const int f10 = w ^ ((L >> 5) & 1);
    const float u0r = G2[10][f10 * 4 + 0], u0i = G2[10][f10 * 4 + 1];
    const float u1r = G2[10][f10 * 4 + 2], u1i = G2[10][f10 * 4 + 3];
    const int ls_hi = (L ^ (L << 1)) & 48;
    const int nsx   = (L ^ (L << 1)) & 15;
    float outv[16];

    __syncthreads();                    // all trip1 reads complete
    if (w == 0) {
        #pragma unroll
        for (int n = 0; n < 16; ++n) {
            buf[L * 17 + n]        = getS(SR, n);
            buf[1088 + L * 17 + n] = getS(SI, n);
        }
    }
    __syncthreads();
    #pragma unroll
    for (int n = 0; n < 16; ++n) {
        const int a = (((n ^ (n << 1)) & 15) | ls_hi) * 17 + (nsx ^ (n >> 3));
        outv[n] = u0r * buf[a] - u0i * buf[1088 + a];
    }
    __syncthreads();
    if (w == 1) {
        #pragma unroll
        for (int n = 0; n < 16; ++n) {
            buf[L * 17 + n]        = getS(SR, n);
            buf[1088 + L * 17 + n] = getS(SI, n);
        }
    }
    __syncthreads();
    #pragma unroll
    for (int n = 0; n < 16; ++n) {
        const int a = (((n ^ (n << 1)) & 15) | ls_hi) * 17 + (nsx ^ (n >> 3));
        outv[n] += u1r * buf[a] - u1i * buf[1088 + a];
    }

    // ---- Epilogue: lane owns 16 consecutive floats, coalesced -----------
    float* orow = out + (size_t)b * DIM + w * 1024 + L * 16;
    #pragma unroll
    for (int k = 0; k < 4; ++k) {
        *(float4*)(orow + 4 * k) =
            make_float4(outv[4*k], outv[4*k+1], outv[4*k+2], outv[4*k+3]);
    }
}

extern "C" void kernel_launch(void* const* d_in, const int* in_sizes, int n_in,
                              void* d_out, int out_size, void* d_ws, size_t ws_size,
                              hipStream_t stream)
{
    const float* theta     = (const float*)d_in[0];
    const int*   positions = (const int*)d_in[1];
    float*       out       = (float*)d_out;
    const int B = in_sizes[1];   // 4096

    pqc_sim_kernel<<<B, 128, 0, stream>>>(theta, positions, out);
}

// Round 8
// 75.830 us; speedup vs baseline: 1.4850x; 1.1392x over previous
//
#include <hip/hip_runtime.h>
#include <math.h>

#define N_QUBITS 11
#define DIM 2048

// ---------------------------------------------------------------------------
// TRANSFER-MATRIX FORMULATION — no statevector, no exchanges.
//
// final = P · V · P · C|0>   where
//   C|0>  : product state, amp(i) = prod_q c_q(i_q), c_q(x) = U1_q[x][0]
//   P     : fused CNOT ladder, dest j <- src f(j), f(j) = j ^ (j<<1)
//           (validated R3-R7 on HW)
//   V     : tensor product of layer-2 gates V_q = U2_q
// Expanding:  out[j] = Re SUM_x prod_q V_q[b_q, x_q] * c_q(x_q ^ x_{q-1}),
// with b = f(j), x_{-1} = 0 — a bond-2 chain of 2x2 complex transfer steps:
//   T_11 = (1,1);  T_q[h] = sum_xq V_q[b_q,xq] c_q(xq^h) T_{q+1}[xq]
//   out[j] = Re sum_x0 V_0[b_0,x0] c_0(x0) T_1[x0]
// Consistency: V=I gives s(f(f(j))) = double-ladder (correct); dropping V,P
// gives prod c_q(b_q) = the R6/R7 HW-validated layer-1 closed form.
//
// Per-(q,b) coefficients precomputed in LDS:  K[q][b] = {d0,d1,e0,e1},
//   d0 = V[b,0]c(0), d1 = V[b,1]c(1), e0 = V[b,0]c(1), e1 = V[b,1]c(0)
// step:  T'[0] = d0*T0 + d1*T1 ;  T'[1] = e0*T0 + e1*T1   (4 cmul)
// Last two factors folded into 4 precomputed row-vectors
//   UM(n0,b1) = u(n0) · M_1(b1),  out = Re( UM · T_2 )     (4 FMA/output)
//
// Two waves per block, one block per batch element: j = 1024w + 16L + n.
//   b0=n0, b1=n1^n0, b2=n2^n1, b3=n3^n2, b4=L0^n3,
//   b(5+k) = bit k of (L^(L>>1)), b10 = w^L5.
// Per lane: 6 tail steps + (2+4+8) tree steps + 16 dots; ~46 ds_read_b128
// (2-way broadcast = conflict-free), ZERO barriers after the table build,
// peak ~56 live floats (under the 64-VGPR clamp seen in R2/R4/R6).
// ---------------------------------------------------------------------------

struct cT { float r0, i0, r1, i1; };   // 2-entry complex column vector

static __device__ __forceinline__
cT step(const float* Krow, const cT& T)
{
    const float4 A = *(const float4*)(Krow);      // d0, d1
    const float4 B = *(const float4*)(Krow + 4);  // e0, e1
    cT o;
    o.r0 = A.x * T.r0 - A.y * T.i0 + A.z * T.r1 - A.w * T.i1;
    o.i0 = A.x * T.i0 + A.y * T.r0 + A.z * T.i1 + A.w * T.r1;
    o.r1 = B.x * T.r0 - B.y * T.i0 + B.z * T.r1 - B.w * T.i1;
    o.i1 = B.x * T.i0 + B.y * T.r0 + B.z * T.i1 + B.w * T.r1;
    return o;
}

static __device__ __forceinline__
float redot(const float4& m, const cT& T)
{   // Re( m(0)*T0 + m(1)*T1 )
    return m.x * T.r0 - m.y * T.i0 + m.z * T.r1 - m.w * T.i1;
}

__global__ __launch_bounds__(128)
void pqc_sim_kernel(const float* __restrict__ theta,
                    const int* __restrict__ positions,
                    float* __restrict__ out)
{
    __shared__ float C1[N_QUBITS][4];     // layer-1 col0: c(0)re,im, c(1)re,im
    __shared__ float G2[N_QUBITS][8];     // layer-2 full 2x2 complex
    __shared__ float K[N_QUBITS][2][8];   // transfer coeffs per (q, b)
    __shared__ float UM[2][2][4];         // folded (q=0,q=1) row vectors

    const int t   = threadIdx.x;
    const int b   = blockIdx.x;
    const int pos = positions[b];

    // ---- Phase 1: gates. U = Rz(g)*Ry(b)*Rx(a), angles*0.5 (validated) ----
    if (t < 22) {
        const int l = t / N_QUBITS;
        const int q = t % N_QUBITS;
        const float* th = theta + (((size_t)pos * 2 + l) * (3 * N_QUBITS)) + 3 * q;
        const float a  = th[0] * 0.5f;
        const float bb = th[1] * 0.5f;
        const float g  = th[2] * 0.5f;
        float sa, ca, sb, cb, sg, cg;
        sincosf(a,  &sa, &ca);
        sincosf(bb, &sb, &cb);
        sincosf(g,  &sg, &cg);
        const float m00r =  cb * ca, m00i =  sb * sa;
        const float m01r = -sb * ca, m01i = -cb * sa;
        const float m10r =  sb * ca, m10i = -cb * sa;
        const float m11r =  cb * ca, m11i = -sb * sa;
        const float u00r = m00r * cg + m00i * sg, u00i = m00i * cg - m00r * sg;
        const float u01r = m01r * cg + m01i * sg, u01i = m01i * cg - m01r * sg;
        const float u10r = m10r * cg - m10i * sg, u10i = m10i * cg + m10r * sg;
        const float u11r = m11r * cg - m11i * sg, u11i = m11i * cg + m11r * sg;
        if (l) {
            G2[q][0] = u00r; G2[q][1] = u00i; G2[q][2] = u01r; G2[q][3] = u01i;
            G2[q][4] = u10r; G2[q][5] = u10i; G2[q][6] = u11r; G2[q][7] = u11i;
        } else {
            C1[q][0] = u00r; C1[q][1] = u00i;   // c_q(0)
            C1[q][2] = u10r; C1[q][3] = u10i;   // c_q(1)
        }
    }
    __syncthreads();

    // ---- Phase 2: K table ----
    if (t < 44) {
        const int q = t >> 1, bb = t & 1;
        const float v0r = G2[q][bb * 4 + 0], v0i = G2[q][bb * 4 + 1];
        const float v1r = G2[q][bb * 4 + 2], v1i = G2[q][bb * 4 + 3];
        const float c0r = C1[q][0], c0i = C1[q][1];
        const float c1r = C1[q][2], c1i = C1[q][3];
        K[q][bb][0] = v0r * c0r - v0i * c0i;   // d0 = V[b,0]*c(0)
        K[q][bb][1] = v0r * c0i + v0i * c0r;
        K[q][bb][2] = v1r * c1r - v1i * c1i;   // d1 = V[b,1]*c(1)
        K[q][bb][3] = v1r * c1i + v1i * c1r;
        K[q][bb][4] = v0r * c1r - v0i * c1i;   // e0 = V[b,0]*c(1)
        K[q][bb][5] = v0r * c1i + v0i * c1r;
        K[q][bb][6] = v1r * c0r - v1i * c0i;   // e1 = V[b,1]*c(0)
        K[q][bb][7] = v1r * c0i + v1i * c0r;
    }
    __syncthreads();

    // ---- Phase 3: UM rows. u(n0) = (K[0][n0].d0, K[0][n0].d1);
    // UM[0] = u0*K1.d0 + u1*K1.e0 ; UM[1] = u0*K1.d1 + u1*K1.e1 ----
    if (t < 4) {
        const int n0 = t >> 1, bb = t & 1;
        const float u0r = K[0][n0][0], u0i = K[0][n0][1];
        const float u1r = K[0][n0][2], u1i = K[0][n0][3];
        const float d0r = K[1][bb][0], d0i = K[1][bb][1];
        const float d1r = K[1][bb][2], d1i = K[1][bb][3];
        const float e0r = K[1][bb][4], e0i = K[1][bb][5];
        const float e1r = K[1][bb][6], e1i = K[1][bb][7];
        UM[n0][bb][0] = u0r * d0r - u0i * d0i + u1r * e0r - u1i * e0i;
        UM[n0][bb][1] = u0r * d0i + u0i * d0r + u1r * e0i + u1i * e0r;
        UM[n0][bb][2] = u0r * d1r - u0i * d1i + u1r * e1r - u1i * e1i;
        UM[n0][bb][3] = u0r * d1i + u0i * d1r + u1r * e1i + u1i * e1r;
    }
    __syncthreads();

    // ---- Main: per-lane chain evaluation (no barriers, no exchanges) ----
    const int w = t >> 6, L = t & 63;

    // Tail: q=10 (T=(1,1) folded in), then q=9..5
    cT T;
    {
        const float* Kr = &K[10][w ^ (L >> 5)][0];
        const float4 A = *(const float4*)(Kr);
        const float4 B = *(const float4*)(Kr + 4);
        T.r0 = A.x + A.z;  T.i0 = A.y + A.w;
        T.r1 = B.x + B.z;  T.i1 = B.y + B.w;
    }
    const int z = L ^ (L >> 1);            // z_k = b_{5+k}
    #pragma unroll
    for (int k = 4; k >= 0; --k) {         // q = 9 down to 5
        T = step(&K[5 + k][(z >> k) & 1][0], T);
    }

    const float4 um00 = *(const float4*)&UM[0][0][0];
    const float4 um01 = *(const float4*)&UM[0][1][0];
    const float4 um10 = *(const float4*)&UM[1][0][0];
    const float4 um11 = *(const float4*)&UM[1][1][0];
    const int L0 = L & 1;
    float* orow = out + (size_t)b * DIM + w * 1024 + L * 16;

    #pragma unroll
    for (int n3 = 0; n3 < 2; ++n3) {
        const cT T4 = step(&K[4][L0 ^ n3][0], T);        // b4 = L0^n3
        #pragma unroll
        for (int n2 = 0; n2 < 2; ++n2) {
            const cT T3  = step(&K[3][n3 ^ n2][0], T4);  // b3 = n3^n2
            const cT T2a = step(&K[2][n2][0],     T3);   // n1=0: b2 = n2
            const cT T2b = step(&K[2][n2 ^ 1][0], T3);   // n1=1: b2 = n2^1
            float4 o;
            o.x = redot(um00, T2a);   // n0=0,n1=0: b1=0
            o.y = redot(um11, T2a);   // n0=1,n1=0: b1=1
            o.z = redot(um01, T2b);   // n0=0,n1=1: b1=1
            o.w = redot(um10, T2b);   // n0=1,n1=1: b1=0
            *(float4*)(orow + 4 * n2 + 8 * n3) = o;      // n = 4n2 + 8n3 ...
        }
    }
}

extern "C" void kernel_launch(void* const* d_in, const int* in_sizes, int n_in,
                              void* d_out, int out_size, void* d_ws, size_t ws_size,
                              hipStream_t stream)
{
    const float* theta     = (const float*)d_in[0];
    const int*   positions = (const int*)d_in[1];
    float*       out       = (float*)d_out;
    const int B = in_sizes[1];   // 4096

    pqc_sim_kernel<<<B, 128, 0, stream>>>(theta, positions, out);
}